// Round 1
// baseline (760.254 us; speedup 1.0000x reference)
//
#include <hip/hip_runtime.h>
#include <math.h>

#define BB 16
#define HH 8
#define DD 128
#define BSZ 16
#define LL 4096
#define MAXB 384
#define HID 1024
#define NTOK 4097            // 4080 window+sink + 16 current block + 1 new token
#define SPLITS 16
#define CHUNK 257            // ceil(4097/16)
#define NPART (SPLITS * 4)   // per-wave partials per (b,h)

// ws layout (float offsets)
#define WS_COS 0
#define WS_SIN (4096 * 64)
#define WS_ATTN (2 * 4096 * 64)
#define WS_PO (WS_ATTN + BB * HID)
#define WS_PM (WS_PO + BB * HH * NPART * DD)
#define WS_PL (WS_PM + BB * HH * NPART)

__global__ void rope_table_kernel(float* __restrict__ ws) {
    int idx = blockIdx.x * blockDim.x + threadIdx.x;  // 0..262143
    int pos = idx >> 6;
    int d = idx & 63;
    // match ref: inv_freq = 1/10000^(d/64) rounded to f32; ang = f32(pos)*f32(invf)
    float invf = (float)(1.0 / pow(10000.0, (double)d / 64.0));
    float ang = (float)pos * invf;
    double da = (double)ang;
    ws[WS_COS + idx] = (float)cos(da);
    ws[WS_SIN + idx] = (float)sin(da);
}

__launch_bounds__(256)
__global__ void attn_kernel(const float* __restrict__ q,
                            const float* __restrict__ k,
                            const float* __restrict__ v,
                            const float* __restrict__ kcache,
                            const float* __restrict__ vcache,
                            const int* __restrict__ btab,
                            const int* __restrict__ slen,
                            float* __restrict__ ws) {
    int s = blockIdx.x;   // split
    int bh = blockIdx.y;  // b*H + h
    int b = bh >> 3, h = bh & 7;
    int tid = threadIdx.x;
    int wid = tid >> 6, lane = tid & 63;

    __shared__ int physBase[257];  // element-offset of block start in cache
    __shared__ int posBase[257];
    __shared__ int cntS[257];      // valid slots in this block

    int num_past = slen[b] - 1;
    int mblk = num_past >> 4;
    int rem = num_past & 15;

    for (int i = tid; i < 257; i += 256) {
        int phys, pb, cnt;
        if (i == 0)        { phys = btab[b * MAXB];                 pb = 0;               cnt = 16; }
        else if (i <= 254) { phys = btab[b * MAXB + mblk - 255 + i]; pb = 15 - rem + i * 16; cnt = 16; }
        else if (i == 255) { phys = btab[b * MAXB + mblk];           pb = 4079 - rem;      cnt = rem; }
        else               { phys = 0;                               pb = 4095;            cnt = 1; }
        physBase[i] = phys << 14;  // *BSZ*HH*DD = 16384
        posBase[i] = pb;
        cntS[i] = cnt;
    }
    __syncthreads();

    const float* ctab = ws + WS_COS;
    const float* stab = ws + WS_SIN;

    // rotate q at pos 4095; fold in 1/sqrt(D)
    float q1 = q[b * HID + h * DD + lane];
    float q2 = q[b * HID + h * DD + 64 + lane];
    float c0 = ctab[4095 * 64 + lane], s0 = stab[4095 * 64 + lane];
    const float scale = 0.08838834764831845f;
    float qr1 = (q1 * c0 - q2 * s0) * scale;
    float qr2 = (q2 * c0 + q1 * s0) * scale;

    int t0 = s * CHUNK;
    int t1 = t0 + CHUNK;
    if (t1 > NTOK) t1 = NTOK;

    float m_run = -1e30f, l_run = 0.f, o1 = 0.f, o2 = 0.f;

    for (int t = t0 + wid; t < t1; t += 4) {
        int blk = t >> 4, slot = t & 15;
        int cnt = cntS[blk];
        if (slot >= cnt) continue;  // masked (wave-uniform)
        int pos = posBase[blk] + slot;
        const float* kp;
        const float* vp;
        if (blk == 256) {  // the new token comes from q/k/v inputs
            kp = k + b * HID + h * DD;
            vp = v + b * HID + h * DD;
        } else {
            int base = physBase[blk] + slot * (HH * DD) + h * DD;
            kp = kcache + base;
            vp = vcache + base;
        }
        float k1 = kp[lane], k2 = kp[64 + lane];
        float cc = ctab[pos * 64 + lane], ss = stab[pos * 64 + lane];
        float kr1 = k1 * cc - k2 * ss;
        float kr2 = k2 * cc + k1 * ss;
        float part = qr1 * kr1 + qr2 * kr2;
        #pragma unroll
        for (int off = 32; off; off >>= 1) part += __shfl_xor(part, off, 64);
        float sc = part;  // all lanes hold the score

        float v1 = vp[lane], v2 = vp[64 + lane];
        float mnew = fmaxf(m_run, sc);
        float corr = expf(m_run - mnew);  // ==1 when no new max
        float p = expf(sc - mnew);
        l_run = l_run * corr + p;
        o1 = o1 * corr + p * v1;
        o2 = o2 * corr + p * v2;
        m_run = mnew;
    }

    int pidx = (bh * SPLITS + s) * 4 + wid;
    ws[WS_PO + pidx * DD + lane] = o1;
    ws[WS_PO + pidx * DD + 64 + lane] = o2;
    if (lane == 0) {
        ws[WS_PM + pidx] = m_run;
        ws[WS_PL + pidx] = l_run;
    }
}

__global__ void reduce_kernel(float* __restrict__ ws) {
    int bh = blockIdx.x;     // 0..127
    int tid = threadIdx.x;   // 0..127 (= dim d)
    __shared__ float wexp[NPART], wl[NPART];
    int base = bh * NPART;

    float M = -1e30f;
    for (int p = 0; p < NPART; ++p) M = fmaxf(M, ws[WS_PM + base + p]);

    if (tid < NPART) {
        float w = expf(ws[WS_PM + base + tid] - M);
        wexp[tid] = w;
        wl[tid] = w * ws[WS_PL + base + tid];
    }
    __syncthreads();

    float Lsum = 0.f;
    for (int p = 0; p < NPART; ++p) Lsum += wl[p];

    float O = 0.f;
    for (int p = 0; p < NPART; ++p)
        O += wexp[p] * ws[WS_PO + (base + p) * DD + tid];

    int b = bh >> 3, h = bh & 7;
    ws[WS_ATTN + b * HID + h * DD + tid] = O / Lsum;
}

__launch_bounds__(256)
__global__ void proj_kernel(const float* __restrict__ Wo,
                            const float* __restrict__ ws,
                            float* __restrict__ out) {
    // grid: (16 j-tiles of 64 cols, 8 k-tiles of 128)
    int jt = blockIdx.x, kt = blockIdx.y;
    int tid = threadIdx.x;
    int jl = tid & 63, kk = tid >> 6;  // kk in 0..3
    int j = jt * 64 + jl;
    int kbase = kt * 128;

    __shared__ float sA[BB][128];
    for (int i = tid; i < BB * 128; i += 256) {
        int bb = i >> 7, kx = i & 127;
        sA[bb][kx] = ws[WS_ATTN + bb * HID + kbase + kx];
    }
    __syncthreads();

    float acc[BB];
    #pragma unroll
    for (int bb = 0; bb < BB; ++bb) acc[bb] = 0.f;

    for (int kx = kk * 32; kx < kk * 32 + 32; ++kx) {
        float w = Wo[(kbase + kx) * HID + j];
        #pragma unroll
        for (int bb = 0; bb < BB; ++bb) acc[bb] += sA[bb][kx] * w;
    }

    __shared__ float sOut[4][64][BB];
    #pragma unroll
    for (int bb = 0; bb < BB; ++bb) sOut[kk][jl][bb] = acc[bb];
    __syncthreads();

    if (kk == 0) {
        #pragma unroll
        for (int bb = 0; bb < BB; ++bb) {
            float r = sOut[0][jl][bb] + sOut[1][jl][bb] + sOut[2][jl][bb] + sOut[3][jl][bb];
            atomicAdd(&out[bb * HID + j], r);
        }
    }
}

extern "C" void kernel_launch(void* const* d_in, const int* in_sizes, int n_in,
                              void* d_out, int out_size, void* d_ws, size_t ws_size,
                              hipStream_t stream) {
    const float* q  = (const float*)d_in[0];
    const float* k  = (const float*)d_in[1];
    const float* v  = (const float*)d_in[2];
    // d_in[3] = positions (unused; == seq_lens - 1)
    const float* kc = (const float*)d_in[4];
    const float* vc = (const float*)d_in[5];
    const int* bt   = (const int*)d_in[6];
    const int* sl   = (const int*)d_in[7];
    const float* Wo = (const float*)d_in[8];
    float* out = (float*)d_out;
    float* ws  = (float*)d_ws;

    hipMemsetAsync(d_out, 0, BB * HID * sizeof(float), stream);
    rope_table_kernel<<<1024, 256, 0, stream>>>(ws);
    dim3 ga(SPLITS, BB * HH);
    attn_kernel<<<ga, 256, 0, stream>>>(q, k, v, kc, vc, bt, sl, ws);
    reduce_kernel<<<BB * HH, 128, 0, stream>>>(ws);
    dim3 gp(16, 8);
    proj_kernel<<<gp, 256, 0, stream>>>(Wo, ws, out);
}